// Round 1
// baseline (1074.335 us; speedup 1.0000x reference)
//
#include <hip/hip_runtime.h>
#include <hip/hip_bf16.h>

#define IN_DIM 768
#define HID 128
#define NC 7

typedef __attribute__((ext_vector_type(8))) short bf16x8;
typedef __attribute__((ext_vector_type(4))) float f32x4;

__device__ __forceinline__ ushort f2bf(float f) {
  uint u = __float_as_uint(f);
  u += 0x7fffu + ((u >> 16) & 1u);   // round-to-nearest-even
  return (ushort)(u >> 16);
}
__device__ __forceinline__ float bf2f(ushort h) {
  return __uint_as_float(((uint)h) << 16);
}

// ---------------- CSR build ----------------

__global__ void k_count(const int* __restrict__ dst, int* __restrict__ cnt, int E) {
  int e = blockIdx.x * 256 + threadIdx.x;
  if (e < E) atomicAdd(&cnt[dst[e]], 1);
}

__global__ void k_scan_partial(const int* __restrict__ cnt, int* __restrict__ partials, int N) {
  __shared__ int sm[256];
  int b = blockIdx.x, t = threadIdx.x;
  int base = b * 1024 + t * 4;
  int s = 0;
  #pragma unroll
  for (int j = 0; j < 4; ++j) if (base + j < N) s += cnt[base + j];
  sm[t] = s;
  __syncthreads();
  for (int off = 128; off > 0; off >>= 1) {
    if (t < off) sm[t] += sm[t + off];
    __syncthreads();
  }
  if (t == 0) partials[b] = sm[0];
}

__global__ void k_scan_combine(int* __restrict__ partials, int* __restrict__ rowptr,
                               int nch, int N) {
  __shared__ int sm[128];
  int t = threadIdx.x;
  int v0 = (t < nch) ? partials[t] : 0;
  sm[t] = v0;
  __syncthreads();
  for (int off = 1; off < 128; off <<= 1) {
    int add = (t >= off) ? sm[t - off] : 0;
    __syncthreads();
    sm[t] += add;
    __syncthreads();
  }
  if (t < nch) partials[t] = sm[t] - v0;     // exclusive chunk offset
  if (t == 0) rowptr[N] = sm[127];           // total = E
}

__global__ void k_scan_final(const int* __restrict__ cnt, const int* __restrict__ chunkoff,
                             int* __restrict__ rowptr, int N) {
  __shared__ int sm[256];
  int b = blockIdx.x, t = threadIdx.x;
  int base = b * 1024 + t * 4;
  int v[4]; int s = 0;
  #pragma unroll
  for (int j = 0; j < 4; ++j) { v[j] = (base + j < N) ? cnt[base + j] : 0; s += v[j]; }
  sm[t] = s;
  __syncthreads();
  for (int off = 1; off < 256; off <<= 1) {
    int add = (t >= off) ? sm[t - off] : 0;
    __syncthreads();
    sm[t] += add;
    __syncthreads();
  }
  int excl = sm[t] - s;
  int run = chunkoff[b] + excl;
  #pragma unroll
  for (int j = 0; j < 4; ++j) {
    if (base + j < N) rowptr[base + j] = run;
    run += v[j];
  }
}

__global__ void k_dinv(const int* __restrict__ cnt, float* __restrict__ dinv, int N) {
  int n = blockIdx.x * 256 + threadIdx.x;
  if (n < N) dinv[n] = rsqrtf((float)(cnt[n] + 1));
}

__global__ void k_scatter(const int* __restrict__ src, const int* __restrict__ dst,
                          const int* __restrict__ rowptr, int* __restrict__ cursor,
                          const float* __restrict__ dinv, int2* __restrict__ csr, int E) {
  int e = blockIdx.x * 256 + threadIdx.x;
  if (e >= E) return;
  int d = dst[e], s = src[e];
  int pos = rowptr[d] + atomicAdd(&cursor[d], 1);
  float nrm = dinv[s] * dinv[d];
  csr[pos] = make_int2(s, __float_as_int(nrm));
}

// ---------------- weight convert/transpose ----------------
// W [K][128] f32 row-major -> WT [128][K] bf16
__global__ void k_convW(const float* __restrict__ W, ushort* __restrict__ WT, int K) {
  int i = blockIdx.x * 256 + threadIdx.x;
  if (i >= K * HID) return;
  int k = i >> 7, c = i & 127;
  WT[c * K + k] = f2bf(W[i]);
}

// ---------------- MFMA GEMM: [N,K] @ [K,128] -> bf16 [N,128] ----------------
template<int K, bool AF32>
__global__ __launch_bounds__(256, 2)
void gemm_mfma(const void* __restrict__ Ap, const ushort* __restrict__ WT,
               ushort* __restrict__ Hout, int N) {
  __shared__ ushort lA[128 * 72];   // padded rows: 72 bf16 = 144B (16B aligned)
  __shared__ ushort lB[128 * 72];
  const int tid = threadIdx.x;
  const int lane = tid & 63;
  const int wid = tid >> 6;
  const int wm = wid >> 1, wn = wid & 1;
  const int row0 = blockIdx.x * 128;
  const int lr = lane & 15;
  const int lk = (lane >> 4) * 8;

  f32x4 acc[4][4];
  #pragma unroll
  for (int m = 0; m < 4; ++m)
    #pragma unroll
    for (int n = 0; n < 4; ++n)
      acc[m][n] = (f32x4){0.f, 0.f, 0.f, 0.f};

  for (int k0 = 0; k0 < K; k0 += 64) {
    if constexpr (AF32) {
      const float* A = (const float*)Ap;
      #pragma unroll
      for (int i = 0; i < 8; ++i) {
        int lin = i * 256 + tid;
        int ar = lin >> 4, c4 = lin & 15;
        int gr = row0 + ar;
        float4 v = make_float4(0.f, 0.f, 0.f, 0.f);
        if (gr < N) v = *(const float4*)&A[(size_t)gr * K + k0 + c4 * 4];
        ushort4 h;
        h.x = f2bf(v.x); h.y = f2bf(v.y); h.z = f2bf(v.z); h.w = f2bf(v.w);
        *(ushort4*)&lA[ar * 72 + c4 * 4] = h;
      }
    } else {
      const ushort* A = (const ushort*)Ap;
      #pragma unroll
      for (int i = 0; i < 4; ++i) {
        int lin = i * 256 + tid;
        int ar = lin >> 3, ch = lin & 7;
        int gr = row0 + ar;
        uint4 v = make_uint4(0, 0, 0, 0);
        if (gr < N) v = *(const uint4*)&A[(size_t)gr * K + k0 + ch * 8];
        *(uint4*)&lA[ar * 72 + ch * 8] = v;
      }
    }
    #pragma unroll
    for (int i = 0; i < 4; ++i) {
      int lin = i * 256 + tid;
      int br = lin >> 3, ch = lin & 7;
      *(uint4*)&lB[br * 72 + ch * 8] = *(const uint4*)&WT[br * K + k0 + ch * 8];
    }
    __syncthreads();
    #pragma unroll
    for (int kk = 0; kk < 2; ++kk) {
      bf16x8 av[4], bv[4];
      #pragma unroll
      for (int m = 0; m < 4; ++m)
        av[m] = *(const bf16x8*)&lA[(wm * 64 + m * 16 + lr) * 72 + kk * 32 + lk];
      #pragma unroll
      for (int n = 0; n < 4; ++n)
        bv[n] = *(const bf16x8*)&lB[(wn * 64 + n * 16 + lr) * 72 + kk * 32 + lk];
      #pragma unroll
      for (int m = 0; m < 4; ++m)
        #pragma unroll
        for (int n = 0; n < 4; ++n)
          acc[m][n] = __builtin_amdgcn_mfma_f32_16x16x32_bf16(av[m], bv[n], acc[m][n], 0, 0, 0);
    }
    __syncthreads();
  }

  #pragma unroll
  for (int m = 0; m < 4; ++m) {
    #pragma unroll
    for (int i = 0; i < 4; ++i) {
      int row = row0 + wm * 64 + m * 16 + (lane >> 4) * 4 + i;
      if (row < N) {
        #pragma unroll
        for (int n = 0; n < 4; ++n) {
          int col = wn * 64 + n * 16 + lr;
          Hout[(size_t)row * HID + col] = f2bf(acc[m][n][i]);
        }
      }
    }
  }
}

// ---------------- aggregation: one wave per node, fused self+bias+relu ----------------
__global__ void k_agg(const uint* __restrict__ Hu, const int2* __restrict__ csr,
                      const int* __restrict__ rowptr, const float* __restrict__ dinv,
                      const float* __restrict__ bias, uint* __restrict__ Ou, int N) {
  int w = (blockIdx.x * 256 + threadIdx.x) >> 6;   // node = wave id
  if (w >= N) return;
  int lane = threadIdx.x & 63;
  int start = rowptr[w], end = rowptr[w + 1];
  float di = dinv[w];
  uint hv = Hu[(size_t)w * 64 + lane];
  float self = di * di;
  float a0 = self * bf2f((ushort)(hv & 0xffff));
  float a1 = self * bf2f((ushort)(hv >> 16));
  for (int i = start; i < end; ++i) {
    int2 e = csr[i];
    float nrm = __int_as_float(e.y);
    uint v = Hu[(size_t)e.x * 64 + lane];
    a0 += nrm * bf2f((ushort)(v & 0xffff));
    a1 += nrm * bf2f((ushort)(v >> 16));
  }
  float2 bb = ((const float2*)bias)[lane];
  a0 = fmaxf(a0 + bb.x, 0.f);
  a1 = fmaxf(a1 + bb.y, 0.f);
  Ou[(size_t)w * 64 + lane] = (uint)f2bf(a0) | ((uint)f2bf(a1) << 16);
}

// ---------------- classifier: [N,128] bf16 @ [128,7] + bc -> f32 ----------------
__global__ void k_gemm3(const ushort* __restrict__ A, const float* __restrict__ Wc,
                        const float* __restrict__ bc, float* __restrict__ out, int N) {
  __shared__ float w[HID * NC];
  __shared__ float bb[NC];
  for (int i = threadIdx.x; i < HID * NC; i += 256) w[i] = Wc[i];
  if (threadIdx.x < NC) bb[threadIdx.x] = bc[threadIdx.x];
  __syncthreads();
  int r = blockIdx.x * 256 + threadIdx.x;
  if (r >= N) return;
  float acc[NC];
  #pragma unroll
  for (int c = 0; c < NC; ++c) acc[c] = bb[c];
  const uint* Au = (const uint*)(A + (size_t)r * HID);
  #pragma unroll 4
  for (int kw = 0; kw < HID / 2; ++kw) {
    uint v = Au[kw];
    float v0 = bf2f((ushort)(v & 0xffff));
    float v1 = bf2f((ushort)(v >> 16));
    const float* w0 = &w[(kw * 2) * NC];
    #pragma unroll
    for (int c = 0; c < NC; ++c) acc[c] += v0 * w0[c] + v1 * w0[NC + c];
  }
  #pragma unroll
  for (int c = 0; c < NC; ++c) out[(size_t)r * NC + c] = acc[c];
}

extern "C" void kernel_launch(void* const* d_in, const int* in_sizes, int n_in,
                              void* d_out, int out_size, void* d_ws, size_t ws_size,
                              hipStream_t stream) {
  const float* x  = (const float*)d_in[0];
  const int*   ei = (const int*)d_in[1];
  const float* W1 = (const float*)d_in[2];
  const float* b1 = (const float*)d_in[3];
  const float* W2 = (const float*)d_in[4];
  const float* b2 = (const float*)d_in[5];
  const float* Wc = (const float*)d_in[6];
  const float* bc = (const float*)d_in[7];
  float* out = (float*)d_out;

  const int N = in_sizes[0] / IN_DIM;
  const int E = in_sizes[1] / 2;
  const int* src = ei;
  const int* dst = ei + E;

  char* ws = (char*)d_ws;
  size_t off = 0;
  auto alloc = [&](size_t bytes) -> void* {
    off = (off + 255) & ~(size_t)255;
    void* p = ws + off;
    off += bytes;
    return p;
  };
  ushort* H0     = (ushort*)alloc((size_t)N * HID * 2);
  ushort* H1     = (ushort*)alloc((size_t)N * HID * 2);
  int2*   csr    = (int2*)alloc((size_t)E * 8);
  int*    cnt    = (int*)alloc((size_t)N * 4);
  int*    cursor = (int*)alloc((size_t)N * 4);
  int*    rowptr = (int*)alloc((size_t)(N + 1) * 4);
  float*  dinv   = (float*)alloc((size_t)N * 4);
  int*    partials = (int*)alloc(512);
  ushort* W1T    = (ushort*)alloc((size_t)IN_DIM * HID * 2);
  ushort* W2T    = (ushort*)alloc((size_t)HID * HID * 2);

  hipMemsetAsync(cnt, 0, (size_t)N * 4, stream);
  hipMemsetAsync(cursor, 0, (size_t)N * 4, stream);

  k_convW<<<(IN_DIM * HID + 255) / 256, 256, 0, stream>>>(W1, W1T, IN_DIM);
  k_convW<<<(HID * HID + 255) / 256, 256, 0, stream>>>(W2, W2T, HID);

  k_count<<<(E + 255) / 256, 256, 0, stream>>>(dst, cnt, E);
  int nch = (N + 1023) >> 10;
  k_scan_partial<<<nch, 256, 0, stream>>>(cnt, partials, N);
  k_scan_combine<<<1, 128, 0, stream>>>(partials, rowptr, nch, N);
  k_scan_final<<<nch, 256, 0, stream>>>(cnt, partials, rowptr, N);
  k_dinv<<<(N + 255) / 256, 256, 0, stream>>>(cnt, dinv, N);
  k_scatter<<<(E + 255) / 256, 256, 0, stream>>>(src, dst, rowptr, cursor, dinv, csr, E);

  gemm_mfma<IN_DIM, true><<<(N + 127) / 128, 256, 0, stream>>>(x, W1T, H0, N);
  k_agg<<<(N + 3) / 4, 256, 0, stream>>>((const uint*)H0, csr, rowptr, dinv, b1, (uint*)H1, N);
  gemm_mfma<HID, false><<<(N + 127) / 128, 256, 0, stream>>>(H1, W2T, H0, N);
  k_agg<<<(N + 3) / 4, 256, 0, stream>>>((const uint*)H0, csr, rowptr, dinv, b2, (uint*)H1, N);
  k_gemm3<<<(N + 255) / 256, 256, 0, stream>>>(H1, Wc, bc, out, N);
}

// Round 2
// 733.109 us; speedup vs baseline: 1.4654x; 1.4654x over previous
//
#include <hip/hip_runtime.h>
#include <hip/hip_bf16.h>

#define IN_DIM 768
#define HID 128
#define NC 7

typedef __attribute__((ext_vector_type(8))) short bf16x8;
typedef __attribute__((ext_vector_type(4))) float f32x4;

__device__ __forceinline__ ushort f2bf(float f) {
  uint u = __float_as_uint(f);
  u += 0x7fffu + ((u >> 16) & 1u);   // round-to-nearest-even
  return (ushort)(u >> 16);
}
__device__ __forceinline__ float bf2f(ushort h) {
  return __uint_as_float(((uint)h) << 16);
}

// ---------------- CSR build ----------------

__global__ void k_count(const int* __restrict__ dst, int* __restrict__ cnt, int E) {
  int e = blockIdx.x * 256 + threadIdx.x;
  if (e < E) atomicAdd(&cnt[dst[e]], 1);
}

__global__ void k_scan_partial(const int* __restrict__ cnt, int* __restrict__ partials, int N) {
  __shared__ int sm[256];
  int b = blockIdx.x, t = threadIdx.x;
  int base = b * 1024 + t * 4;
  int s = 0;
  #pragma unroll
  for (int j = 0; j < 4; ++j) if (base + j < N) s += cnt[base + j];
  sm[t] = s;
  __syncthreads();
  for (int off = 128; off > 0; off >>= 1) {
    if (t < off) sm[t] += sm[t + off];
    __syncthreads();
  }
  if (t == 0) partials[b] = sm[0];
}

__global__ void k_scan_combine(int* __restrict__ partials, int* __restrict__ rowptr,
                               int nch, int N) {
  __shared__ int sm[128];
  int t = threadIdx.x;
  int v0 = (t < nch) ? partials[t] : 0;
  sm[t] = v0;
  __syncthreads();
  for (int off = 1; off < 128; off <<= 1) {
    int add = (t >= off) ? sm[t - off] : 0;
    __syncthreads();
    sm[t] += add;
    __syncthreads();
  }
  if (t < nch) partials[t] = sm[t] - v0;     // exclusive chunk offset
  if (t == 0) rowptr[N] = sm[127];           // total = E
}

__global__ void k_scan_final(const int* __restrict__ cnt, const int* __restrict__ chunkoff,
                             int* __restrict__ rowptr, int N) {
  __shared__ int sm[256];
  int b = blockIdx.x, t = threadIdx.x;
  int base = b * 1024 + t * 4;
  int v[4]; int s = 0;
  #pragma unroll
  for (int j = 0; j < 4; ++j) { v[j] = (base + j < N) ? cnt[base + j] : 0; s += v[j]; }
  sm[t] = s;
  __syncthreads();
  for (int off = 1; off < 256; off <<= 1) {
    int add = (t >= off) ? sm[t - off] : 0;
    __syncthreads();
    sm[t] += add;
    __syncthreads();
  }
  int excl = sm[t] - s;
  int run = chunkoff[b] + excl;
  #pragma unroll
  for (int j = 0; j < 4; ++j) {
    if (base + j < N) rowptr[base + j] = run;
    run += v[j];
  }
}

__global__ void k_dinv(const int* __restrict__ cnt, float* __restrict__ dinv, int N) {
  int n = blockIdx.x * 256 + threadIdx.x;
  if (n < N) dinv[n] = rsqrtf((float)(cnt[n] + 1));
}

__global__ void k_scatter(const int* __restrict__ src, const int* __restrict__ dst,
                          const int* __restrict__ rowptr, int* __restrict__ cursor,
                          const float* __restrict__ dinv, int2* __restrict__ csr, int E) {
  int e = blockIdx.x * 256 + threadIdx.x;
  if (e >= E) return;
  int d = dst[e], s = src[e];
  int pos = rowptr[d] + atomicAdd(&cursor[d], 1);
  float nrm = dinv[s] * dinv[d];
  csr[pos] = make_int2(s, __float_as_int(nrm));
}

// ---------------- weight convert/transpose ----------------
// W [K][128] f32 row-major -> WT [128][K] bf16
__global__ void k_convW(const float* __restrict__ W, ushort* __restrict__ WT, int K) {
  int i = blockIdx.x * 256 + threadIdx.x;
  if (i >= K * HID) return;
  int k = i >> 7, c = i & 127;
  WT[c * K + k] = f2bf(W[i]);
}

// ---------------- MFMA GEMM: [N,K] @ [K,128] -> bf16 [N,128] ----------------
template<int K, bool AF32>
__global__ __launch_bounds__(256, 2)
void gemm_mfma(const void* __restrict__ Ap, const ushort* __restrict__ WT,
               ushort* __restrict__ Hout, int N) {
  __shared__ ushort lA[128 * 72];   // padded rows: 72 bf16 = 144B (16B aligned)
  __shared__ ushort lB[128 * 72];
  const int tid = threadIdx.x;
  const int lane = tid & 63;
  const int wid = tid >> 6;
  const int wm = wid >> 1, wn = wid & 1;
  const int row0 = blockIdx.x * 128;
  const int lr = lane & 15;
  const int lk = (lane >> 4) * 8;

  f32x4 acc[4][4];
  #pragma unroll
  for (int m = 0; m < 4; ++m)
    #pragma unroll
    for (int n = 0; n < 4; ++n)
      acc[m][n] = (f32x4){0.f, 0.f, 0.f, 0.f};

  for (int k0 = 0; k0 < K; k0 += 64) {
    if constexpr (AF32) {
      const float* A = (const float*)Ap;
      #pragma unroll
      for (int i = 0; i < 8; ++i) {
        int lin = i * 256 + tid;
        int ar = lin >> 4, c4 = lin & 15;
        int gr = row0 + ar;
        float4 v = make_float4(0.f, 0.f, 0.f, 0.f);
        if (gr < N) v = *(const float4*)&A[(size_t)gr * K + k0 + c4 * 4];
        ushort4 h;
        h.x = f2bf(v.x); h.y = f2bf(v.y); h.z = f2bf(v.z); h.w = f2bf(v.w);
        *(ushort4*)&lA[ar * 72 + c4 * 4] = h;
      }
    } else {
      const ushort* A = (const ushort*)Ap;
      #pragma unroll
      for (int i = 0; i < 4; ++i) {
        int lin = i * 256 + tid;
        int ar = lin >> 3, ch = lin & 7;
        int gr = row0 + ar;
        uint4 v = make_uint4(0, 0, 0, 0);
        if (gr < N) v = *(const uint4*)&A[(size_t)gr * K + k0 + ch * 8];
        *(uint4*)&lA[ar * 72 + ch * 8] = v;
      }
    }
    #pragma unroll
    for (int i = 0; i < 4; ++i) {
      int lin = i * 256 + tid;
      int br = lin >> 3, ch = lin & 7;
      *(uint4*)&lB[br * 72 + ch * 8] = *(const uint4*)&WT[br * K + k0 + ch * 8];
    }
    __syncthreads();
    #pragma unroll
    for (int kk = 0; kk < 2; ++kk) {
      bf16x8 av[4], bv[4];
      #pragma unroll
      for (int m = 0; m < 4; ++m)
        av[m] = *(const bf16x8*)&lA[(wm * 64 + m * 16 + lr) * 72 + kk * 32 + lk];
      #pragma unroll
      for (int n = 0; n < 4; ++n)
        bv[n] = *(const bf16x8*)&lB[(wn * 64 + n * 16 + lr) * 72 + kk * 32 + lk];
      #pragma unroll
      for (int m = 0; m < 4; ++m)
        #pragma unroll
        for (int n = 0; n < 4; ++n)
          acc[m][n] = __builtin_amdgcn_mfma_f32_16x16x32_bf16(av[m], bv[n], acc[m][n], 0, 0, 0);
    }
    __syncthreads();
  }

  #pragma unroll
  for (int m = 0; m < 4; ++m) {
    #pragma unroll
    for (int i = 0; i < 4; ++i) {
      int row = row0 + wm * 64 + m * 16 + (lane >> 4) * 4 + i;
      if (row < N) {
        #pragma unroll
        for (int n = 0; n < 4; ++n) {
          int col = wn * 64 + n * 16 + lr;
          Hout[(size_t)row * HID + col] = f2bf(acc[m][n][i]);
        }
      }
    }
  }
}

// ---------------- aggregation: one wave per node, 8-deep gather pipeline ----------------
__global__ __launch_bounds__(256)
void k_agg(const uint* __restrict__ Hu, const int2* __restrict__ csr,
           const int* __restrict__ rowptr, const float* __restrict__ dinv,
           const float* __restrict__ bias, uint* __restrict__ Ou, int N) {
  int w = (blockIdx.x * 256 + threadIdx.x) >> 6;   // node = wave id
  if (w >= N) return;
  int lane = threadIdx.x & 63;
  int start = rowptr[w], end = rowptr[w + 1];
  float di = dinv[w];
  uint hv = Hu[(size_t)w * 64 + lane];
  float self = di * di;
  float a0 = self * bf2f((ushort)(hv & 0xffff));
  float a1 = self * bf2f((ushort)(hv >> 16));

  int i = start;
  // 8-deep unroll: batch CSR loads, then 8 independent row gathers in flight
  for (; i + 8 <= end; i += 8) {
    int2 e[8];
    #pragma unroll
    for (int j = 0; j < 8; ++j) e[j] = csr[i + j];
    uint v[8];
    #pragma unroll
    for (int j = 0; j < 8; ++j) v[j] = Hu[(size_t)e[j].x * 64 + lane];
    #pragma unroll
    for (int j = 0; j < 8; ++j) {
      float nrm = __int_as_float(e[j].y);
      a0 += nrm * bf2f((ushort)(v[j] & 0xffff));
      a1 += nrm * bf2f((ushort)(v[j] >> 16));
    }
  }
  // tail
  for (; i < end; ++i) {
    int2 e = csr[i];
    float nrm = __int_as_float(e.y);
    uint v = Hu[(size_t)e.x * 64 + lane];
    a0 += nrm * bf2f((ushort)(v & 0xffff));
    a1 += nrm * bf2f((ushort)(v >> 16));
  }

  float2 bb = ((const float2*)bias)[lane];
  a0 = fmaxf(a0 + bb.x, 0.f);
  a1 = fmaxf(a1 + bb.y, 0.f);
  Ou[(size_t)w * 64 + lane] = (uint)f2bf(a0) | ((uint)f2bf(a1) << 16);
}

// ---------------- classifier: [N,128] bf16 @ [128,7] + bc -> f32 ----------------
__global__ void k_gemm3(const ushort* __restrict__ A, const float* __restrict__ Wc,
                        const float* __restrict__ bc, float* __restrict__ out, int N) {
  __shared__ float w[HID * NC];
  __shared__ float bb[NC];
  for (int i = threadIdx.x; i < HID * NC; i += 256) w[i] = Wc[i];
  if (threadIdx.x < NC) bb[threadIdx.x] = bc[threadIdx.x];
  __syncthreads();
  int r = blockIdx.x * 256 + threadIdx.x;
  if (r >= N) return;
  float acc[NC];
  #pragma unroll
  for (int c = 0; c < NC; ++c) acc[c] = bb[c];
  const uint* Au = (const uint*)(A + (size_t)r * HID);
  #pragma unroll 4
  for (int kw = 0; kw < HID / 2; ++kw) {
    uint v = Au[kw];
    float v0 = bf2f((ushort)(v & 0xffff));
    float v1 = bf2f((ushort)(v >> 16));
    const float* w0 = &w[(kw * 2) * NC];
    #pragma unroll
    for (int c = 0; c < NC; ++c) acc[c] += v0 * w0[c] + v1 * w0[NC + c];
  }
  #pragma unroll
  for (int c = 0; c < NC; ++c) out[(size_t)r * NC + c] = acc[c];
}

extern "C" void kernel_launch(void* const* d_in, const int* in_sizes, int n_in,
                              void* d_out, int out_size, void* d_ws, size_t ws_size,
                              hipStream_t stream) {
  const float* x  = (const float*)d_in[0];
  const int*   ei = (const int*)d_in[1];
  const float* W1 = (const float*)d_in[2];
  const float* b1 = (const float*)d_in[3];
  const float* W2 = (const float*)d_in[4];
  const float* b2 = (const float*)d_in[5];
  const float* Wc = (const float*)d_in[6];
  const float* bc = (const float*)d_in[7];
  float* out = (float*)d_out;

  const int N = in_sizes[0] / IN_DIM;
  const int E = in_sizes[1] / 2;
  const int* src = ei;
  const int* dst = ei + E;

  char* ws = (char*)d_ws;
  size_t off = 0;
  auto alloc = [&](size_t bytes) -> void* {
    off = (off + 255) & ~(size_t)255;
    void* p = ws + off;
    off += bytes;
    return p;
  };
  ushort* H0     = (ushort*)alloc((size_t)N * HID * 2);
  ushort* H1     = (ushort*)alloc((size_t)N * HID * 2);
  int2*   csr    = (int2*)alloc((size_t)E * 8);
  int*    cnt    = (int*)alloc((size_t)N * 4);
  int*    cursor = (int*)alloc((size_t)N * 4);
  int*    rowptr = (int*)alloc((size_t)(N + 1) * 4);
  float*  dinv   = (float*)alloc((size_t)N * 4);
  int*    partials = (int*)alloc(512);
  ushort* W1T    = (ushort*)alloc((size_t)IN_DIM * HID * 2);
  ushort* W2T    = (ushort*)alloc((size_t)HID * HID * 2);

  hipMemsetAsync(cnt, 0, (size_t)N * 4, stream);
  hipMemsetAsync(cursor, 0, (size_t)N * 4, stream);

  k_convW<<<(IN_DIM * HID + 255) / 256, 256, 0, stream>>>(W1, W1T, IN_DIM);
  k_convW<<<(HID * HID + 255) / 256, 256, 0, stream>>>(W2, W2T, HID);

  k_count<<<(E + 255) / 256, 256, 0, stream>>>(dst, cnt, E);
  int nch = (N + 1023) >> 10;
  k_scan_partial<<<nch, 256, 0, stream>>>(cnt, partials, N);
  k_scan_combine<<<1, 128, 0, stream>>>(partials, rowptr, nch, N);
  k_scan_final<<<nch, 256, 0, stream>>>(cnt, partials, rowptr, N);
  k_dinv<<<(N + 255) / 256, 256, 0, stream>>>(cnt, dinv, N);
  k_scatter<<<(E + 255) / 256, 256, 0, stream>>>(src, dst, rowptr, cursor, dinv, csr, E);

  gemm_mfma<IN_DIM, true><<<(N + 127) / 128, 256, 0, stream>>>(x, W1T, H0, N);
  k_agg<<<(N + 3) / 4, 256, 0, stream>>>((const uint*)H0, csr, rowptr, dinv, b1, (uint*)H1, N);
  gemm_mfma<HID, false><<<(N + 127) / 128, 256, 0, stream>>>(H1, W2T, H0, N);
  k_agg<<<(N + 3) / 4, 256, 0, stream>>>((const uint*)H0, csr, rowptr, dinv, b2, (uint*)H1, N);
  k_gemm3<<<(N + 255) / 256, 256, 0, stream>>>(H1, Wc, bc, out, N);
}

// Round 3
// 653.549 us; speedup vs baseline: 1.6438x; 1.1217x over previous
//
#include <hip/hip_runtime.h>
#include <hip/hip_bf16.h>

#define IN_DIM 768
#define HID 128
#define NC 7

typedef __attribute__((ext_vector_type(8))) short bf16x8;
typedef __attribute__((ext_vector_type(4))) float f32x4;

__device__ __forceinline__ ushort f2bf(float f) {
  uint u = __float_as_uint(f);
  u += 0x7fffu + ((u >> 16) & 1u);   // round-to-nearest-even
  return (ushort)(u >> 16);
}
__device__ __forceinline__ float bf2f(ushort h) {
  return __uint_as_float(((uint)h) << 16);
}

// ---------------- x f32 -> bf16 (streaming) ----------------
__global__ __launch_bounds__(256) void k_convX(const float* __restrict__ x,
                                               ushort* __restrict__ xb, long total) {
  long i = ((long)blockIdx.x * 256 + threadIdx.x) * 8;
  if (i >= total) return;
  float4 a = *(const float4*)&x[i];
  float4 b = *(const float4*)&x[i + 4];
  union { ushort4 h[2]; uint4 u; } pk;
  pk.h[0] = make_ushort4(f2bf(a.x), f2bf(a.y), f2bf(a.z), f2bf(a.w));
  pk.h[1] = make_ushort4(f2bf(b.x), f2bf(b.y), f2bf(b.z), f2bf(b.w));
  *(uint4*)&xb[i] = pk.u;
}

// ---------------- CSR build ----------------

// count indegree AND assign within-node position (removes atomics from scatter)
__global__ __launch_bounds__(256) void k_count(const int* __restrict__ dst,
                                               int* __restrict__ cnt,
                                               int* __restrict__ pos, int E) {
  int e0 = (blockIdx.x * 256 + threadIdx.x) * 4;
  if (e0 + 4 <= E) {
    int4 d = *(const int4*)&dst[e0];
    int4 p;
    p.x = atomicAdd(&cnt[d.x], 1);
    p.y = atomicAdd(&cnt[d.y], 1);
    p.z = atomicAdd(&cnt[d.z], 1);
    p.w = atomicAdd(&cnt[d.w], 1);
    *(int4*)&pos[e0] = p;
  } else {
    for (int e = e0; e < E; ++e) pos[e] = atomicAdd(&cnt[dst[e]], 1);
  }
}

__global__ void k_scan_partial(const int* __restrict__ cnt, int* __restrict__ partials, int N) {
  __shared__ int sm[256];
  int b = blockIdx.x, t = threadIdx.x;
  int base = b * 1024 + t * 4;
  int s = 0;
  #pragma unroll
  for (int j = 0; j < 4; ++j) if (base + j < N) s += cnt[base + j];
  sm[t] = s;
  __syncthreads();
  for (int off = 128; off > 0; off >>= 1) {
    if (t < off) sm[t] += sm[t + off];
    __syncthreads();
  }
  if (t == 0) partials[b] = sm[0];
}

__global__ void k_scan_combine(int* __restrict__ partials, int* __restrict__ rowptr,
                               int nch, int N) {
  __shared__ int sm[128];
  int t = threadIdx.x;
  int v0 = (t < nch) ? partials[t] : 0;
  sm[t] = v0;
  __syncthreads();
  for (int off = 1; off < 128; off <<= 1) {
    int add = (t >= off) ? sm[t - off] : 0;
    __syncthreads();
    sm[t] += add;
    __syncthreads();
  }
  if (t < nch) partials[t] = sm[t] - v0;     // exclusive chunk offset
  if (t == 0) rowptr[N] = sm[127];           // total = E
}

__global__ void k_scan_final(const int* __restrict__ cnt, const int* __restrict__ chunkoff,
                             int* __restrict__ rowptr, int N) {
  __shared__ int sm[256];
  int b = blockIdx.x, t = threadIdx.x;
  int base = b * 1024 + t * 4;
  int v[4]; int s = 0;
  #pragma unroll
  for (int j = 0; j < 4; ++j) { v[j] = (base + j < N) ? cnt[base + j] : 0; s += v[j]; }
  sm[t] = s;
  __syncthreads();
  for (int off = 1; off < 256; off <<= 1) {
    int add = (t >= off) ? sm[t - off] : 0;
    __syncthreads();
    sm[t] += add;
    __syncthreads();
  }
  int excl = sm[t] - s;
  int run = chunkoff[b] + excl;
  #pragma unroll
  for (int j = 0; j < 4; ++j) {
    if (base + j < N) rowptr[base + j] = run;
    run += v[j];
  }
}

__global__ void k_dinv(const int* __restrict__ cnt, float* __restrict__ dinv, int N) {
  int n = blockIdx.x * 256 + threadIdx.x;
  if (n < N) dinv[n] = rsqrtf((float)(cnt[n] + 1));
}

// atomic-free scatter, 8-deep batched for MLP
__global__ __launch_bounds__(256)
void k_scatter(const int* __restrict__ src, const int* __restrict__ dst,
               const int* __restrict__ pos, const int* __restrict__ rowptr,
               const float* __restrict__ dinv, int2* __restrict__ csr, int E) {
  int e0 = (blockIdx.x * 256 + threadIdx.x) * 8;
  if (e0 + 8 <= E) {
    int s[8], d[8], p[8];
    *(int4*)&s[0] = *(const int4*)&src[e0];
    *(int4*)&s[4] = *(const int4*)&src[e0 + 4];
    *(int4*)&d[0] = *(const int4*)&dst[e0];
    *(int4*)&d[4] = *(const int4*)&dst[e0 + 4];
    *(int4*)&p[0] = *(const int4*)&pos[e0];
    *(int4*)&p[4] = *(const int4*)&pos[e0 + 4];
    int rp[8]; float dvs[8], dvd[8];
    #pragma unroll
    for (int j = 0; j < 8; ++j) rp[j] = rowptr[d[j]];
    #pragma unroll
    for (int j = 0; j < 8; ++j) dvs[j] = dinv[s[j]];
    #pragma unroll
    for (int j = 0; j < 8; ++j) dvd[j] = dinv[d[j]];
    #pragma unroll
    for (int j = 0; j < 8; ++j)
      csr[rp[j] + p[j]] = make_int2(s[j], __float_as_int(dvs[j] * dvd[j]));
  } else {
    for (int e = e0; e < E; ++e) {
      int dd = dst[e], ss = src[e];
      csr[rowptr[dd] + pos[e]] = make_int2(ss, __float_as_int(dinv[ss] * dinv[dd]));
    }
  }
}

// ---------------- weight convert/transpose ----------------
// W [K][128] f32 row-major -> WT [128][K] bf16
__global__ void k_convW(const float* __restrict__ W, ushort* __restrict__ WT, int K) {
  int i = blockIdx.x * 256 + threadIdx.x;
  if (i >= K * HID) return;
  int k = i >> 7, c = i & 127;
  WT[c * K + k] = f2bf(W[i]);
}

// ---------------- MFMA GEMM (m97-style): bf16 [N,K] @ WT[128,K] -> bf16 [N,128] ----------------
// global_load_lds width=16, XOR-swizzled source (rule 21), 2-phase dbuf prefetch
template<int K>
__global__ __launch_bounds__(256)
void gemm_bf(const ushort* __restrict__ A, const ushort* __restrict__ WT,
             ushort* __restrict__ Hout, const int N) {
  __shared__ ushort lA[2][128 * 64];   // 16 KB per buffer, linear (gload_lds dest)
  __shared__ ushort lB[2][128 * 64];
  const int tid = threadIdx.x;
  const int lane = tid & 63;
  const int wid = tid >> 6;
  const int wm = wid >> 1, wn = wid & 1;
  const int row0 = blockIdx.x * 128;
  const int lr = lane & 15;
  const int lk8 = lane >> 4;           // 0..3

  // stage one BK=64 tile of A and B into buffer `buf`.
  // LDS chunk i (r=i>>3, slot=i&7) holds global (row r, c16 = slot ^ (r&7)):
  // inverse-swizzled source + swizzled read = consistent involution.
  auto stage = [&](int buf, int k0) {
    #pragma unroll
    for (int j = 0; j < 4; ++j) {
      int i = j * 256 + tid;
      int r = i >> 3;
      int c = ((i & 7) ^ (r & 7)) * 8;          // element offset within BK
      int ga = row0 + r; ga = ga < N ? ga : N - 1;
      __builtin_amdgcn_global_load_lds((const uint*)(A + (size_t)ga * K + k0 + c),
                                       (uint*)&lA[buf][i * 8], 16, 0, 0);
      __builtin_amdgcn_global_load_lds((const uint*)(WT + (size_t)r * K + k0 + c),
                                       (uint*)&lB[buf][i * 8], 16, 0, 0);
    }
  };

  f32x4 acc[4][4];
  #pragma unroll
  for (int m = 0; m < 4; ++m)
    #pragma unroll
    for (int n = 0; n < 4; ++n)
      acc[m][n] = (f32x4){0.f, 0.f, 0.f, 0.f};

  constexpr int NT = K / 64;
  stage(0, 0);
  __syncthreads();

  for (int t = 0; t < NT; ++t) {
    const int cur = t & 1;
    if (t + 1 < NT) stage(cur ^ 1, (t + 1) * 64);
    #pragma unroll
    for (int kk = 0; kk < 2; ++kk) {
      bf16x8 av[4], bv[4];
      #pragma unroll
      for (int m = 0; m < 4; ++m) {
        int R = wm * 64 + m * 16 + lr;
        int slot = (kk * 4 + lk8) ^ (R & 7);
        av[m] = *(const bf16x8*)&lA[cur][R * 64 + slot * 8];
      }
      #pragma unroll
      for (int n = 0; n < 4; ++n) {
        int C = wn * 64 + n * 16 + lr;
        int slot = (kk * 4 + lk8) ^ (C & 7);
        bv[n] = *(const bf16x8*)&lB[cur][C * 64 + slot * 8];
      }
      #pragma unroll
      for (int m = 0; m < 4; ++m)
        #pragma unroll
        for (int n = 0; n < 4; ++n)
          acc[m][n] = __builtin_amdgcn_mfma_f32_16x16x32_bf16(av[m], bv[n], acc[m][n], 0, 0, 0);
    }
    __syncthreads();   // drains vmcnt (stage t+1 complete) + readers done
  }

  #pragma unroll
  for (int m = 0; m < 4; ++m) {
    #pragma unroll
    for (int i = 0; i < 4; ++i) {
      int row = row0 + wm * 64 + m * 16 + (lane >> 4) * 4 + i;
      if (row < N) {
        #pragma unroll
        for (int n = 0; n < 4; ++n) {
          int col = wn * 64 + n * 16 + lr;
          Hout[(size_t)row * HID + col] = f2bf(acc[m][n][i]);
        }
      }
    }
  }
}

// ---------------- aggregation core: 16/4/1-deep gather pipeline ----------------
__device__ __forceinline__ float2 agg_edges(const uint* __restrict__ Hu,
                                            const int2* __restrict__ csr,
                                            int start, int end, int lane,
                                            float a0, float a1) {
  int i = start;
  for (; i + 16 <= end; i += 16) {
    int2 e[16]; uint v[16];
    #pragma unroll
    for (int j = 0; j < 16; ++j) e[j] = csr[i + j];
    #pragma unroll
    for (int j = 0; j < 16; ++j) v[j] = Hu[(size_t)e[j].x * 64 + lane];
    #pragma unroll
    for (int j = 0; j < 16; ++j) {
      float nrm = __int_as_float(e[j].y);
      a0 += nrm * bf2f((ushort)(v[j] & 0xffff));
      a1 += nrm * bf2f((ushort)(v[j] >> 16));
    }
  }
  for (; i + 4 <= end; i += 4) {
    int2 e[4]; uint v[4];
    #pragma unroll
    for (int j = 0; j < 4; ++j) e[j] = csr[i + j];
    #pragma unroll
    for (int j = 0; j < 4; ++j) v[j] = Hu[(size_t)e[j].x * 64 + lane];
    #pragma unroll
    for (int j = 0; j < 4; ++j) {
      float nrm = __int_as_float(e[j].y);
      a0 += nrm * bf2f((ushort)(v[j] & 0xffff));
      a1 += nrm * bf2f((ushort)(v[j] >> 16));
    }
  }
  for (; i < end; ++i) {
    int2 e = csr[i];
    float nrm = __int_as_float(e.y);
    uint v = Hu[(size_t)e.x * 64 + lane];
    a0 += nrm * bf2f((ushort)(v & 0xffff));
    a1 += nrm * bf2f((ushort)(v >> 16));
  }
  return make_float2(a0, a1);
}

__global__ __launch_bounds__(256)
void k_agg(const uint* __restrict__ Hu, const int2* __restrict__ csr,
           const int* __restrict__ rowptr, const float* __restrict__ dinv,
           const float* __restrict__ bias, uint* __restrict__ Ou, int N) {
  int w = (blockIdx.x * 256 + threadIdx.x) >> 6;
  if (w >= N) return;
  int lane = threadIdx.x & 63;
  int start = rowptr[w], end = rowptr[w + 1];
  float di = dinv[w];
  uint hv = Hu[(size_t)w * 64 + lane];
  float self = di * di;
  float a0 = self * bf2f((ushort)(hv & 0xffff));
  float a1 = self * bf2f((ushort)(hv >> 16));
  float2 r = agg_edges(Hu, csr, start, end, lane, a0, a1);
  float2 bb = ((const float2*)bias)[lane];
  a0 = fmaxf(r.x + bb.x, 0.f);
  a1 = fmaxf(r.y + bb.y, 0.f);
  Ou[(size_t)w * 64 + lane] = (uint)f2bf(a0) | ((uint)f2bf(a1) << 16);
}

// layer-2 aggregation with fused classifier: logits = relu(h2) @ Wc + bc
__global__ __launch_bounds__(256)
void k_agg_final(const uint* __restrict__ Hu, const int2* __restrict__ csr,
                 const int* __restrict__ rowptr, const float* __restrict__ dinv,
                 const float* __restrict__ bias, const float* __restrict__ Wc,
                 const float* __restrict__ bc, float* __restrict__ out, int N) {
  int w = (blockIdx.x * 256 + threadIdx.x) >> 6;
  if (w >= N) return;
  int lane = threadIdx.x & 63;
  int start = rowptr[w], end = rowptr[w + 1];
  float di = dinv[w];
  uint hv = Hu[(size_t)w * 64 + lane];
  float self = di * di;
  float a0 = self * bf2f((ushort)(hv & 0xffff));
  float a1 = self * bf2f((ushort)(hv >> 16));
  float2 r = agg_edges(Hu, csr, start, end, lane, a0, a1);
  float2 bb = ((const float2*)bias)[lane];
  a0 = fmaxf(r.x + bb.x, 0.f);
  a1 = fmaxf(r.y + bb.y, 0.f);
  // classifier: lane owns dims 2*lane, 2*lane+1
  const float* w0 = &Wc[(2 * lane) * NC];
  #pragma unroll
  for (int c = 0; c < NC; ++c) {
    float s = a0 * w0[c] + a1 * w0[NC + c];
    #pragma unroll
    for (int off = 32; off > 0; off >>= 1) s += __shfl_xor(s, off, 64);
    if (lane == 0) out[(size_t)w * NC + c] = s + bc[c];
  }
}

extern "C" void kernel_launch(void* const* d_in, const int* in_sizes, int n_in,
                              void* d_out, int out_size, void* d_ws, size_t ws_size,
                              hipStream_t stream) {
  const float* x  = (const float*)d_in[0];
  const int*   ei = (const int*)d_in[1];
  const float* W1 = (const float*)d_in[2];
  const float* b1 = (const float*)d_in[3];
  const float* W2 = (const float*)d_in[4];
  const float* b2 = (const float*)d_in[5];
  const float* Wc = (const float*)d_in[6];
  const float* bc = (const float*)d_in[7];
  float* out = (float*)d_out;

  const int N = in_sizes[0] / IN_DIM;
  const int E = in_sizes[1] / 2;
  const int* src = ei;
  const int* dst = ei + E;

  char* ws = (char*)d_ws;
  size_t off = 0;
  auto alloc = [&](size_t bytes) -> void* {
    off = (off + 255) & ~(size_t)255;
    void* p = ws + off;
    off += bytes;
    return p;
  };
  ushort* xbf    = (ushort*)alloc((size_t)N * IN_DIM * 2);
  ushort* H0     = (ushort*)alloc((size_t)N * HID * 2);
  ushort* H1     = (ushort*)alloc((size_t)N * HID * 2);
  int2*   csr    = (int2*)alloc((size_t)E * 8);
  int*    cnt    = (int*)alloc((size_t)N * 4);
  int*    pos    = (int*)alloc((size_t)E * 4);
  int*    rowptr = (int*)alloc((size_t)(N + 1) * 4);
  float*  dinv   = (float*)alloc((size_t)N * 4);
  int*    partials = (int*)alloc(512);
  ushort* W1T    = (ushort*)alloc((size_t)IN_DIM * HID * 2);
  ushort* W2T    = (ushort*)alloc((size_t)HID * HID * 2);

  hipMemsetAsync(cnt, 0, (size_t)N * 4, stream);

  k_convW<<<(IN_DIM * HID + 255) / 256, 256, 0, stream>>>(W1, W1T, IN_DIM);
  k_convW<<<(HID * HID + 255) / 256, 256, 0, stream>>>(W2, W2T, HID);
  long totalx = (long)N * IN_DIM;
  k_convX<<<(int)((totalx / 8 + 255) / 256), 256, 0, stream>>>(x, xbf, totalx);

  k_count<<<(E + 1023) / 1024, 256, 0, stream>>>(dst, cnt, pos, E);
  int nch = (N + 1023) >> 10;
  k_scan_partial<<<nch, 256, 0, stream>>>(cnt, partials, N);
  k_scan_combine<<<1, 128, 0, stream>>>(partials, rowptr, nch, N);
  k_scan_final<<<nch, 256, 0, stream>>>(cnt, partials, rowptr, N);
  k_dinv<<<(N + 255) / 256, 256, 0, stream>>>(cnt, dinv, N);
  k_scatter<<<(E + 2047) / 2048, 256, 0, stream>>>(src, dst, pos, rowptr, dinv, csr, E);

  gemm_bf<IN_DIM><<<(N + 127) / 128, 256, 0, stream>>>(xbf, W1T, H0, N);
  k_agg<<<(N + 3) / 4, 256, 0, stream>>>((const uint*)H0, csr, rowptr, dinv, b1, (uint*)H1, N);
  gemm_bf<HID><<<(N + 127) / 128, 256, 0, stream>>>(H1, W2T, H0, N);
  k_agg_final<<<(N + 3) / 4, 256, 0, stream>>>((const uint*)H0, csr, rowptr, dinv, b2,
                                               Wc, bc, out, N);
}

// Round 4
// 585.170 us; speedup vs baseline: 1.8359x; 1.1169x over previous
//
#include <hip/hip_runtime.h>
#include <hip/hip_bf16.h>

#define IN_DIM 768
#define HID 128
#define NC 7

typedef __attribute__((ext_vector_type(8))) short bf16x8;
typedef __attribute__((ext_vector_type(4))) float f32x4;

__device__ __forceinline__ ushort f2bf(float f) {
  uint u = __float_as_uint(f);
  u += 0x7fffu + ((u >> 16) & 1u);   // round-to-nearest-even
  return (ushort)(u >> 16);
}
__device__ __forceinline__ float lof(uint v) { return __uint_as_float(v << 16); }
__device__ __forceinline__ float hif(uint v) { return __uint_as_float(v & 0xffff0000u); }

// ---------------- CSR build ----------------

// count indegree AND assign within-node position
__global__ __launch_bounds__(256) void k_count(const int* __restrict__ dst,
                                               int* __restrict__ cnt,
                                               int* __restrict__ pos, int E) {
  int e0 = (blockIdx.x * 256 + threadIdx.x) * 4;
  if (e0 + 4 <= E) {
    int4 d = *(const int4*)&dst[e0];
    int4 p;
    p.x = atomicAdd(&cnt[d.x], 1);
    p.y = atomicAdd(&cnt[d.y], 1);
    p.z = atomicAdd(&cnt[d.z], 1);
    p.w = atomicAdd(&cnt[d.w], 1);
    *(int4*)&pos[e0] = p;
  } else {
    for (int e = e0; e < E; ++e) pos[e] = atomicAdd(&cnt[dst[e]], 1);
  }
}

// scans operate on counts rounded up to multiple of 4 (CSR row padding)
__device__ __forceinline__ int pad4(int c) { return (c + 3) & ~3; }

__global__ void k_scan_partial(const int* __restrict__ cnt, int* __restrict__ partials, int N) {
  __shared__ int sm[256];
  int b = blockIdx.x, t = threadIdx.x;
  int base = b * 1024 + t * 4;
  int s = 0;
  #pragma unroll
  for (int j = 0; j < 4; ++j) if (base + j < N) s += pad4(cnt[base + j]);
  sm[t] = s;
  __syncthreads();
  for (int off = 128; off > 0; off >>= 1) {
    if (t < off) sm[t] += sm[t + off];
    __syncthreads();
  }
  if (t == 0) partials[b] = sm[0];
}

__global__ void k_scan_combine(int* __restrict__ partials, int* __restrict__ rowptr,
                               int nch, int N) {
  __shared__ int sm[128];
  int t = threadIdx.x;
  int v0 = (t < nch) ? partials[t] : 0;
  sm[t] = v0;
  __syncthreads();
  for (int off = 1; off < 128; off <<= 1) {
    int add = (t >= off) ? sm[t - off] : 0;
    __syncthreads();
    sm[t] += add;
    __syncthreads();
  }
  if (t < nch) partials[t] = sm[t] - v0;     // exclusive chunk offset
  if (t == 0) rowptr[N] = sm[127];           // total (padded) <= E + 3N
}

__global__ void k_scan_final(const int* __restrict__ cnt, const int* __restrict__ chunkoff,
                             int* __restrict__ rowptr, int N) {
  __shared__ int sm[256];
  int b = blockIdx.x, t = threadIdx.x;
  int base = b * 1024 + t * 4;
  int v[4]; int s = 0;
  #pragma unroll
  for (int j = 0; j < 4; ++j) { v[j] = (base + j < N) ? pad4(cnt[base + j]) : 0; s += v[j]; }
  sm[t] = s;
  __syncthreads();
  for (int off = 1; off < 256; off <<= 1) {
    int add = (t >= off) ? sm[t - off] : 0;
    __syncthreads();
    sm[t] += add;
    __syncthreads();
  }
  int excl = sm[t] - s;
  int run = chunkoff[b] + excl;
  #pragma unroll
  for (int j = 0; j < 4; ++j) {
    if (base + j < N) rowptr[base + j] = run;
    run += v[j];
  }
}

// dinv over N+1 entries; dinv[N] = 0 (pad node contributes nothing)
__global__ void k_dinv(const int* __restrict__ cnt, float* __restrict__ dinv, int N) {
  int n = blockIdx.x * 256 + threadIdx.x;
  if (n <= N) dinv[n] = (n < N) ? rsqrtf((float)(cnt[n] + 1)) : 0.f;
}

__global__ void k_fill(int* __restrict__ p, int val, int total) {
  int i = (blockIdx.x * 256 + threadIdx.x) * 4;
  if (i + 4 <= total) {
    *(int4*)&p[i] = make_int4(val, val, val, val);
  } else {
    for (; i < total; ++i) p[i] = val;
  }
}

// atomic-free scatter: srcs_sorted[rowptr[d] + pos[e]] = src[e]
__global__ __launch_bounds__(256)
void k_scatter(const int* __restrict__ src, const int* __restrict__ dst,
               const int* __restrict__ pos, const int* __restrict__ rowptr,
               int* __restrict__ srcs, int E) {
  int e0 = (blockIdx.x * 256 + threadIdx.x) * 8;
  if (e0 + 8 <= E) {
    int s[8], d[8], p[8];
    *(int4*)&s[0] = *(const int4*)&src[e0];
    *(int4*)&s[4] = *(const int4*)&src[e0 + 4];
    *(int4*)&d[0] = *(const int4*)&dst[e0];
    *(int4*)&d[4] = *(const int4*)&dst[e0 + 4];
    *(int4*)&p[0] = *(const int4*)&pos[e0];
    *(int4*)&p[4] = *(const int4*)&pos[e0 + 4];
    int rp[8];
    #pragma unroll
    for (int j = 0; j < 8; ++j) rp[j] = rowptr[d[j]];
    #pragma unroll
    for (int j = 0; j < 8; ++j) srcs[rp[j] + p[j]] = s[j];
  } else {
    for (int e = e0; e < E; ++e) srcs[rowptr[dst[e]] + pos[e]] = src[e];
  }
}

// ---------------- weight convert/transpose ----------------
// W [K][128] f32 row-major -> WT [128][K] bf16
__global__ void k_convW(const float* __restrict__ W, ushort* __restrict__ WT, int K) {
  int i = blockIdx.x * 256 + threadIdx.x;
  if (i >= K * HID) return;
  int k = i >> 7, c = i & 127;
  WT[c * K + k] = f2bf(W[i]);
}

// ---------------- MFMA GEMM: A [N,K] @ WT[128,K] -> bf16 [N,128] ----------------
// AF32: A is f32, reg-staged with fused cvt + swizzled ds_write (T14 split).
// else: A is bf16, staged via global_load_lds w16 + inverse-swizzled source.
template<int K, bool AF32>
__global__ __launch_bounds__(256)
void gemm_bf(const void* __restrict__ Ap, const ushort* __restrict__ WT,
             ushort* __restrict__ Hout, const int N) {
  __shared__ ushort lA[2][128 * 64];
  __shared__ ushort lB[2][128 * 64];
  const int tid = threadIdx.x;
  const int lane = tid & 63;
  const int wid = tid >> 6;
  const int wm = wid >> 1, wn = wid & 1;
  const int row0 = blockIdx.x * 128;
  const int lr = lane & 15;
  const int lk8 = lane >> 4;           // 0..3
  const ushort* Abf = (const ushort*)Ap;
  const float*  Af  = (const float*)Ap;

  auto stageB = [&](int buf, int k0) {
    #pragma unroll
    for (int j = 0; j < 4; ++j) {
      int i = j * 256 + tid;
      int r = i >> 3;
      int c = ((i & 7) ^ (r & 7)) * 8;
      __builtin_amdgcn_global_load_lds((const uint*)(WT + (size_t)r * K + k0 + c),
                                       (uint*)&lB[buf][i * 8], 16, 0, 0);
    }
  };
  auto stageA_lds = [&](int buf, int k0) {
    #pragma unroll
    for (int j = 0; j < 4; ++j) {
      int i = j * 256 + tid;
      int r = i >> 3;
      int c = ((i & 7) ^ (r & 7)) * 8;
      int ga = row0 + r; ga = ga < N ? ga : N - 1;
      __builtin_amdgcn_global_load_lds((const uint*)(Abf + (size_t)ga * K + k0 + c),
                                       (uint*)&lA[buf][i * 8], 16, 0, 0);
    }
  };

  float4 fa[8];
  auto loadA = [&](int k0) {           // f32 path: 4 chunks = 8 float4 into regs
    #pragma unroll
    for (int j = 0; j < 4; ++j) {
      int i = j * 256 + tid;
      int r = i >> 3;
      int c = (i & 7) * 8;
      int ga = row0 + r; ga = ga < N ? ga : N - 1;
      const float* p = Af + (size_t)ga * K + k0 + c;
      fa[j * 2]     = *(const float4*)p;
      fa[j * 2 + 1] = *(const float4*)(p + 4);
    }
  };
  auto writeA = [&](int buf) {         // cvt + swizzled ds_write_b128
    #pragma unroll
    for (int j = 0; j < 4; ++j) {
      int i = j * 256 + tid;
      int r = i >> 3;
      int slot = (i & 7) ^ (r & 7);
      float4 u = fa[j * 2], v = fa[j * 2 + 1];
      uint4 pk;
      pk.x = (uint)f2bf(u.x) | ((uint)f2bf(u.y) << 16);
      pk.y = (uint)f2bf(u.z) | ((uint)f2bf(u.w) << 16);
      pk.z = (uint)f2bf(v.x) | ((uint)f2bf(v.y) << 16);
      pk.w = (uint)f2bf(v.z) | ((uint)f2bf(v.w) << 16);
      *(uint4*)&lA[buf][r * 64 + slot * 8] = pk;
    }
  };

  f32x4 acc[4][4];
  #pragma unroll
  for (int m = 0; m < 4; ++m)
    #pragma unroll
    for (int n = 0; n < 4; ++n)
      acc[m][n] = (f32x4){0.f, 0.f, 0.f, 0.f};

  constexpr int NT = K / 64;
  if constexpr (AF32) {
    loadA(0); stageB(0, 0); writeA(0);
  } else {
    stageA_lds(0, 0); stageB(0, 0);
  }
  __syncthreads();

  for (int t = 0; t < NT; ++t) {
    const int cur = t & 1;
    if (t + 1 < NT) {
      if constexpr (AF32) loadA((t + 1) * 64);
      else stageA_lds(cur ^ 1, (t + 1) * 64);
      stageB(cur ^ 1, (t + 1) * 64);
    }
    #pragma unroll
    for (int kk = 0; kk < 2; ++kk) {
      bf16x8 av[4], bv[4];
      #pragma unroll
      for (int m = 0; m < 4; ++m) {
        int R = wm * 64 + m * 16 + lr;
        int slot = (kk * 4 + lk8) ^ (R & 7);
        av[m] = *(const bf16x8*)&lA[cur][R * 64 + slot * 8];
      }
      #pragma unroll
      for (int n = 0; n < 4; ++n) {
        int C = wn * 64 + n * 16 + lr;
        int slot = (kk * 4 + lk8) ^ (C & 7);
        bv[n] = *(const bf16x8*)&lB[cur][C * 64 + slot * 8];
      }
      #pragma unroll
      for (int m = 0; m < 4; ++m)
        #pragma unroll
        for (int n = 0; n < 4; ++n)
          acc[m][n] = __builtin_amdgcn_mfma_f32_16x16x32_bf16(av[m], bv[n], acc[m][n], 0, 0, 0);
    }
    if (t + 1 < NT) {
      if constexpr (AF32) writeA(cur ^ 1);
    }
    __syncthreads();
  }

  #pragma unroll
  for (int m = 0; m < 4; ++m) {
    #pragma unroll
    for (int i = 0; i < 4; ++i) {
      int row = row0 + wm * 64 + m * 16 + (lane >> 4) * 4 + i;
      if (row < N) {
        #pragma unroll
        for (int n = 0; n < 4; ++n) {
          int col = wn * 64 + n * 16 + lr;
          Hout[(size_t)row * HID + col] = f2bf(acc[m][n][i]);
        }
      }
    }
  }
}

// ---------------- aggregation: named-var deep gather pipeline ----------------
// dinv[dst] factored out: acc = dinv[d]*h_self (init), + sum dinv[s]*h[s];
// final = dinv[d]*acc + bias.

#define GATHER1(s, w, h, idx) \
  int s = idx; float w = dinv[s]; uint h = Hu[(size_t)s * 64 + lane];

__device__ __forceinline__ void agg_b16(const uint* __restrict__ Hu,
                                        const int* __restrict__ srcs,
                                        const float* __restrict__ dinv,
                                        int i, int lane, float& a0, float& a1) {
  int4 sa = *(const int4*)&srcs[i];
  int4 sb = *(const int4*)&srcs[i + 4];
  int4 sc = *(const int4*)&srcs[i + 8];
  int4 sd = *(const int4*)&srcs[i + 12];
  GATHER1(s0, w0, h0, sa.x) GATHER1(s1, w1, h1, sa.y)
  GATHER1(s2, w2, h2, sa.z) GATHER1(s3, w3, h3, sa.w)
  GATHER1(s4, w4, h4, sb.x) GATHER1(s5, w5, h5, sb.y)
  GATHER1(s6, w6, h6, sb.z) GATHER1(s7, w7, h7, sb.w)
  GATHER1(s8, w8, h8, sc.x) GATHER1(s9, w9, h9, sc.y)
  GATHER1(sA, wA, hA, sc.z) GATHER1(sB, wB, hB, sc.w)
  GATHER1(sC, wC, hC, sd.x) GATHER1(sD, wD, hD, sd.y)
  GATHER1(sE, wE, hE, sd.z) GATHER1(sF, wF, hF, sd.w)
  __builtin_amdgcn_sched_barrier(0);   // keep all 32 loads issued before consumption
  a0 += w0 * lof(h0); a1 += w0 * hif(h0);
  a0 += w1 * lof(h1); a1 += w1 * hif(h1);
  a0 += w2 * lof(h2); a1 += w2 * hif(h2);
  a0 += w3 * lof(h3); a1 += w3 * hif(h3);
  a0 += w4 * lof(h4); a1 += w4 * hif(h4);
  a0 += w5 * lof(h5); a1 += w5 * hif(h5);
  a0 += w6 * lof(h6); a1 += w6 * hif(h6);
  a0 += w7 * lof(h7); a1 += w7 * hif(h7);
  a0 += w8 * lof(h8); a1 += w8 * hif(h8);
  a0 += w9 * lof(h9); a1 += w9 * hif(h9);
  a0 += wA * lof(hA); a1 += wA * hif(hA);
  a0 += wB * lof(hB); a1 += wB * hif(hB);
  a0 += wC * lof(hC); a1 += wC * hif(hC);
  a0 += wD * lof(hD); a1 += wD * hif(hD);
  a0 += wE * lof(hE); a1 += wE * hif(hE);
  a0 += wF * lof(hF); a1 += wF * hif(hF);
}

__device__ __forceinline__ void agg_b4(const uint* __restrict__ Hu,
                                       const int* __restrict__ srcs,
                                       const float* __restrict__ dinv,
                                       int i, int lane, float& a0, float& a1) {
  int4 sa = *(const int4*)&srcs[i];
  GATHER1(s0, w0, h0, sa.x) GATHER1(s1, w1, h1, sa.y)
  GATHER1(s2, w2, h2, sa.z) GATHER1(s3, w3, h3, sa.w)
  __builtin_amdgcn_sched_barrier(0);
  a0 += w0 * lof(h0); a1 += w0 * hif(h0);
  a0 += w1 * lof(h1); a1 += w1 * hif(h1);
  a0 += w2 * lof(h2); a1 += w2 * hif(h2);
  a0 += w3 * lof(h3); a1 += w3 * hif(h3);
}

__global__ __launch_bounds__(256)
void k_agg(const uint* __restrict__ Hu, const int* __restrict__ srcs,
           const int* __restrict__ rowptr, const float* __restrict__ dinv,
           const float* __restrict__ bias, uint* __restrict__ Ou, int N) {
  int w = (blockIdx.x * 256 + threadIdx.x) >> 6;
  if (w >= N) return;
  int lane = threadIdx.x & 63;
  int start = rowptr[w], end = rowptr[w + 1];   // padded to x4
  float di = dinv[w];
  uint hv = Hu[(size_t)w * 64 + lane];
  float a0 = di * lof(hv);
  float a1 = di * hif(hv);
  int i = start;
  for (; i + 16 <= end; i += 16) agg_b16(Hu, srcs, dinv, i, lane, a0, a1);
  for (; i < end; i += 4)        agg_b4(Hu, srcs, dinv, i, lane, a0, a1);
  float2 bb = ((const float2*)bias)[lane];
  a0 = fmaxf(di * a0 + bb.x, 0.f);
  a1 = fmaxf(di * a1 + bb.y, 0.f);
  Ou[(size_t)w * 64 + lane] = (uint)f2bf(a0) | ((uint)f2bf(a1) << 16);
}

// layer-2 aggregation with fused classifier: logits = relu(h2) @ Wc + bc
__global__ __launch_bounds__(256)
void k_agg_final(const uint* __restrict__ Hu, const int* __restrict__ srcs,
                 const int* __restrict__ rowptr, const float* __restrict__ dinv,
                 const float* __restrict__ bias, const float* __restrict__ Wc,
                 const float* __restrict__ bc, float* __restrict__ out, int N) {
  int w = (blockIdx.x * 256 + threadIdx.x) >> 6;
  if (w >= N) return;
  int lane = threadIdx.x & 63;
  int start = rowptr[w], end = rowptr[w + 1];
  float di = dinv[w];
  uint hv = Hu[(size_t)w * 64 + lane];
  float a0 = di * lof(hv);
  float a1 = di * hif(hv);
  int i = start;
  for (; i + 16 <= end; i += 16) agg_b16(Hu, srcs, dinv, i, lane, a0, a1);
  for (; i < end; i += 4)        agg_b4(Hu, srcs, dinv, i, lane, a0, a1);
  float2 bb = ((const float2*)bias)[lane];
  a0 = fmaxf(di * a0 + bb.x, 0.f);
  a1 = fmaxf(di * a1 + bb.y, 0.f);
  // classifier: lane owns dims 2*lane, 2*lane+1
  const float* w0 = &Wc[(2 * lane) * NC];
  #pragma unroll
  for (int c = 0; c < NC; ++c) {
    float s = a0 * w0[c] + a1 * w0[NC + c];
    #pragma unroll
    for (int off = 32; off > 0; off >>= 1) s += __shfl_xor(s, off, 64);
    if (lane == 0) out[(size_t)w * NC + c] = s + bc[c];
  }
}

extern "C" void kernel_launch(void* const* d_in, const int* in_sizes, int n_in,
                              void* d_out, int out_size, void* d_ws, size_t ws_size,
                              hipStream_t stream) {
  const float* x  = (const float*)d_in[0];
  const int*   ei = (const int*)d_in[1];
  const float* W1 = (const float*)d_in[2];
  const float* b1 = (const float*)d_in[3];
  const float* W2 = (const float*)d_in[4];
  const float* b2 = (const float*)d_in[5];
  const float* Wc = (const float*)d_in[6];
  const float* bc = (const float*)d_in[7];
  float* out = (float*)d_out;

  const int N = in_sizes[0] / IN_DIM;
  const int E = in_sizes[1] / 2;
  const int* src = ei;
  const int* dst = ei + E;
  const int CSRCAP = E + 3 * N + 64;   // upper bound on padded total

  char* ws = (char*)d_ws;
  size_t off = 0;
  auto alloc = [&](size_t bytes) -> void* {
    off = (off + 255) & ~(size_t)255;
    void* p = ws + off;
    off += bytes;
    return p;
  };
  ushort* H0     = (ushort*)alloc((size_t)(N + 1) * HID * 2);
  ushort* H1     = (ushort*)alloc((size_t)(N + 1) * HID * 2);
  int*    srcs   = (int*)alloc((size_t)CSRCAP * 4);
  int*    cnt    = (int*)alloc((size_t)N * 4);
  int*    pos    = (int*)alloc((size_t)E * 4);
  int*    rowptr = (int*)alloc((size_t)(N + 1) * 4);
  float*  dinv   = (float*)alloc((size_t)(N + 1) * 4);
  int*    partials = (int*)alloc(512);
  ushort* W1T    = (ushort*)alloc((size_t)IN_DIM * HID * 2);
  ushort* W2T    = (ushort*)alloc((size_t)HID * HID * 2);

  hipMemsetAsync(cnt, 0, (size_t)N * 4, stream);

  k_convW<<<(IN_DIM * HID + 255) / 256, 256, 0, stream>>>(W1, W1T, IN_DIM);
  k_convW<<<(HID * HID + 255) / 256, 256, 0, stream>>>(W2, W2T, HID);

  k_count<<<(E + 1023) / 1024, 256, 0, stream>>>(dst, cnt, pos, E);
  int nch = (N + 1023) >> 10;
  k_scan_partial<<<nch, 256, 0, stream>>>(cnt, partials, N);
  k_scan_combine<<<1, 128, 0, stream>>>(partials, rowptr, nch, N);
  k_scan_final<<<nch, 256, 0, stream>>>(cnt, partials, rowptr, N);
  k_dinv<<<(N + 256) / 256, 256, 0, stream>>>(cnt, dinv, N);
  k_fill<<<(CSRCAP + 1023) / 1024, 256, 0, stream>>>(srcs, N, CSRCAP);
  k_scatter<<<(E + 2047) / 2048, 256, 0, stream>>>(src, dst, pos, rowptr, srcs, E);

  gemm_bf<IN_DIM, true><<<(N + 127) / 128, 256, 0, stream>>>(x, W1T, H0, N);
  k_agg<<<(N + 3) / 4, 256, 0, stream>>>((const uint*)H0, srcs, rowptr, dinv, b1, (uint*)H1, N);
  gemm_bf<HID, false><<<(N + 127) / 128, 256, 0, stream>>>(H1, W2T, H0, N);
  k_agg_final<<<(N + 3) / 4, 256, 0, stream>>>((const uint*)H0, srcs, rowptr, dinv, b2,
                                               Wc, bc, out, N);
}